// Round 1
// baseline (1177.235 us; speedup 1.0000x reference)
//
#include <hip/hip_runtime.h>
#include <hip/hip_bf16.h>
#include <stdint.h>

#define D 128

typedef __attribute__((ext_vector_type(8))) short short8;
typedef __attribute__((ext_vector_type(4))) float f32x4;

__device__ inline unsigned short f2bf(float f) {
    union { float f; uint32_t u; } v; v.f = f;
    uint32_t u = v.u;
    uint32_t r = u + 0x7FFFu + ((u >> 16) & 1u);   // RNE
    return (unsigned short)(r >> 16);
}

__device__ inline float bf2f(uint32_t ubf) {
    union { uint32_t u; float f; } v; v.u = ubf << 16; return v.f;
}

// ---- prep: Wt[w][c][k] = bf16(W_w[k][c])  (transposed so MFMA B-frag reads are contiguous)
__global__ void prep_weights(const float* __restrict__ W0, const float* __restrict__ W1,
                             const float* __restrict__ W2, unsigned short* __restrict__ Wt) {
    int idx = blockIdx.x * blockDim.x + threadIdx.x;
    if (idx >= 3 * D * D) return;
    int w = idx / (D * D);
    int rem = idx - w * D * D;
    int c = rem / D, k = rem - c * D;
    const float* W = (w == 0) ? W0 : ((w == 1) ? W1 : W2);
    Wt[idx] = f2bf(W[k * D + c]);
}

// ---- init out1/out2 with bias (scatter-add accumulates on top; must run every call)
__global__ void init_out(float* __restrict__ out1, float* __restrict__ out2,
                         const float* __restrict__ b1, const float* __restrict__ b2, int total) {
    int idx = blockIdx.x * blockDim.x + threadIdx.x;
    if (idx >= total) return;
    int c = idx & (D - 1);
    out1[idx] = b1[c];
    out2[idx] = b2[c];
}

// ---- fused GEMM: out0 = x@Wln + bln (f32), h1 = bf16(x@W1), h2 = bf16(x@W2)
// 128-row tile per block, 4 waves, mfma_f32_16x16x32_bf16, XOR-swizzled LDS.
__launch_bounds__(256, 2)
__global__ void gemm3(const float* __restrict__ x, const unsigned short* __restrict__ Wt,
                      const float* __restrict__ bln, float* __restrict__ out0,
                      unsigned short* __restrict__ h1, unsigned short* __restrict__ h2, int N) {
    __shared__ char lA[D * 256];   // 128 rows x 256B (128 bf16)
    __shared__ char lB[D * 256];
    const int tid = threadIdx.x;
    const int r0 = blockIdx.x * 128;

    // stage A: x[r0..r0+128) f32 -> bf16, swizzled
    for (int i = 0; i < 16; ++i) {
        int idx4 = i * 256 + tid;        // float4 index in tile
        int row = idx4 >> 5;             // 32 float4 per row
        int k4 = idx4 & 31;
        float4 v = make_float4(0.f, 0.f, 0.f, 0.f);
        int grow = r0 + row;
        if (grow < N) v = *(const float4*)(x + (size_t)grow * D + k4 * 4);
        uint32_t lo = (uint32_t)f2bf(v.x) | ((uint32_t)f2bf(v.y) << 16);
        uint32_t hi = (uint32_t)f2bf(v.z) | ((uint32_t)f2bf(v.w) << 16);
        int byte = row * 256 + k4 * 8;
        byte ^= (row & 7) << 4;
        *(uint2*)(lA + byte) = make_uint2(lo, hi);
    }

    const int wv = tid >> 6, lane = tid & 63;
    const int lr = lane & 15, lk = lane >> 4;

    for (int widx = 0; widx < 3; ++widx) {
        __syncthreads();   // previous iteration's lB reads done (also orders lA writes on widx==0)
        const uint4* src = (const uint4*)(Wt + widx * D * D);
        for (int i = 0; i < 8; ++i) {
            int idx16 = i * 256 + tid;   // 16B chunk index
            int row = idx16 >> 4;
            int k8 = idx16 & 15;
            uint4 v = src[idx16];
            int byte = row * 256 + k8 * 16;
            byte ^= (row & 7) << 4;
            *(uint4*)(lB + byte) = v;
        }
        __syncthreads();

        f32x4 acc[2][8];
        for (int r = 0; r < 2; ++r)
            for (int c = 0; c < 8; ++c) acc[r][c] = (f32x4)(0.f);

        for (int ks = 0; ks < 4; ++ks) {
            int kbyte = ks * 64 + lk * 16;
            short8 a[2], b[8];
            for (int r = 0; r < 2; ++r) {
                int row = wv * 32 + r * 16 + lr;
                int byte = row * 256 + kbyte;
                byte ^= (row & 7) << 4;
                a[r] = *(const short8*)(lA + byte);
            }
            for (int c = 0; c < 8; ++c) {
                int row = c * 16 + lr;
                int byte = row * 256 + kbyte;
                byte ^= (row & 7) << 4;
                b[c] = *(const short8*)(lB + byte);
            }
            for (int r = 0; r < 2; ++r)
                for (int c = 0; c < 8; ++c)
                    acc[r][c] = __builtin_amdgcn_mfma_f32_16x16x32_bf16(a[r], b[c], acc[r][c], 0, 0, 0);
        }

        // epilogue: C/D mapping col=lane&15, row=(lane>>4)*4+i  [verified m89/m91]
        for (int r = 0; r < 2; ++r) {
            for (int c = 0; c < 8; ++c) {
                int col = c * 16 + lr;
                for (int i = 0; i < 4; ++i) {
                    int row = r0 + wv * 32 + r * 16 + lk * 4 + i;
                    if (row >= N) continue;
                    float val = acc[r][c][i];
                    size_t off = (size_t)row * D + col;
                    if (widx == 0)      out0[off] = val + bln[col];
                    else if (widx == 1) h1[off] = f2bf(val);
                    else                h2[off] = f2bf(val);
                }
            }
        }
    }
}

// ---- scatter: one wave per edge, 2 features per lane, f32 atomics
__global__ void scatter_add(const int* __restrict__ ei, const float* __restrict__ ew,
                            const unsigned short* __restrict__ h, float* __restrict__ out, int E) {
    int gid = blockIdx.x * blockDim.x + threadIdx.x;
    int e = gid >> 6;
    int lane = gid & 63;
    if (e >= E) return;
    int src = ei[e];
    int dst = ei[E + e];
    float w = ew[e];
    uint32_t pk = *(const uint32_t*)(h + (size_t)src * D + lane * 2);
    float f0 = bf2f(pk & 0xFFFFu);
    float f1 = bf2f(pk >> 16);
    float* o = out + (size_t)dst * D + lane * 2;
    atomicAdd(o, w * f0);
    atomicAdd(o + 1, w * f1);
}

extern "C" void kernel_launch(void* const* d_in, const int* in_sizes, int n_in,
                              void* d_out, int out_size, void* d_ws, size_t ws_size,
                              hipStream_t stream) {
    const float* x   = (const float*)d_in[0];
    const int*   ei1 = (const int*)d_in[1];
    const float* ew1 = (const float*)d_in[2];
    const int*   ei2 = (const int*)d_in[3];
    const float* ew2 = (const float*)d_in[4];
    const float* Wln = (const float*)d_in[5];
    const float* bln = (const float*)d_in[6];
    const float* W1  = (const float*)d_in[7];
    const float* b1  = (const float*)d_in[8];
    const float* W2  = (const float*)d_in[9];
    const float* b2  = (const float*)d_in[10];

    const int N  = in_sizes[0] / D;
    const int E1 = in_sizes[2];
    const int E2 = in_sizes[4];

    float* out0 = (float*)d_out;
    float* out1 = out0 + (size_t)N * D;
    float* out2 = out1 + (size_t)N * D;

    unsigned short* h1 = (unsigned short*)d_ws;
    unsigned short* h2 = h1 + (size_t)N * D;
    unsigned short* Wt = h2 + (size_t)N * D;

    prep_weights<<<(3 * D * D + 255) / 256, 256, 0, stream>>>(Wln, W1, W2, Wt);
    init_out<<<(N * D + 255) / 256, 256, 0, stream>>>(out1, out2, b1, b2, N * D);
    gemm3<<<(N + 127) / 128, 256, 0, stream>>>(x, Wt, bln, out0, h1, h2, N);
    scatter_add<<<((E1 * 64) + 255) / 256, 256, 0, stream>>>(ei1, ew1, h1, out1, E1);
    scatter_add<<<((E2 * 64) + 255) / 256, 256, 0, stream>>>(ei2, ew2, h2, out2, E2);
}

// Round 3
// 408.148 us; speedup vs baseline: 2.8843x; 2.8843x over previous
//
#include <hip/hip_runtime.h>
#include <hip/hip_bf16.h>
#include <stdint.h>

#define D 128

typedef __attribute__((ext_vector_type(8))) short short8;
typedef __attribute__((ext_vector_type(4))) float f32x4;

__device__ inline unsigned short f2bf(float f) {
    union { float f; uint32_t u; } v; v.f = f;
    uint32_t u = v.u;
    uint32_t r = u + 0x7FFFu + ((u >> 16) & 1u);   // RNE
    return (unsigned short)(r >> 16);
}

__device__ inline float bf2f(uint32_t ubf) {
    union { uint32_t u; float f; } v; v.u = ubf << 16; return v.f;
}

// ---- prep: Wt[w][c][k] = bf16(W_w[k][c])
__global__ void prep_weights(const float* __restrict__ W0, const float* __restrict__ W1,
                             const float* __restrict__ W2, unsigned short* __restrict__ Wt) {
    int idx = blockIdx.x * blockDim.x + threadIdx.x;
    if (idx >= 3 * D * D) return;
    int w = idx / (D * D);
    int rem = idx - w * D * D;
    int c = rem / D, k = rem - c * D;
    const float* W = (w == 0) ? W0 : ((w == 1) ? W1 : W2);
    Wt[idx] = f2bf(W[k * D + c]);
}

// ---- zero fill (int), grid-stride
__global__ void zero_k(int* __restrict__ p, int n) {
    for (int i = blockIdx.x * blockDim.x + threadIdx.x; i < n; i += gridDim.x * blockDim.x)
        p[i] = 0;
}

// ---- fused GEMM: out0 = x@Wln + bln (f32), h1 = bf16(x@W1), h2 = bf16(x@W2)
__launch_bounds__(256, 2)
__global__ void gemm3(const float* __restrict__ x, const unsigned short* __restrict__ Wt,
                      const float* __restrict__ bln, float* __restrict__ out0,
                      unsigned short* __restrict__ h1, unsigned short* __restrict__ h2, int N) {
    __shared__ char lA[D * 256];
    __shared__ char lB[D * 256];
    const int tid = threadIdx.x;
    const int r0 = blockIdx.x * 128;

    for (int i = 0; i < 16; ++i) {
        int idx4 = i * 256 + tid;
        int row = idx4 >> 5;
        int k4 = idx4 & 31;
        float4 v = make_float4(0.f, 0.f, 0.f, 0.f);
        int grow = r0 + row;
        if (grow < N) v = *(const float4*)(x + (size_t)grow * D + k4 * 4);
        uint32_t lo = (uint32_t)f2bf(v.x) | ((uint32_t)f2bf(v.y) << 16);
        uint32_t hi = (uint32_t)f2bf(v.z) | ((uint32_t)f2bf(v.w) << 16);
        int byte = row * 256 + k4 * 8;
        byte ^= (row & 7) << 4;
        *(uint2*)(lA + byte) = make_uint2(lo, hi);
    }

    const int wv = tid >> 6, lane = tid & 63;
    const int lr = lane & 15, lk = lane >> 4;

    for (int widx = 0; widx < 3; ++widx) {
        __syncthreads();
        const uint4* src = (const uint4*)(Wt + widx * D * D);
        for (int i = 0; i < 8; ++i) {
            int idx16 = i * 256 + tid;
            int row = idx16 >> 4;
            int k8 = idx16 & 15;
            uint4 v = src[idx16];
            int byte = row * 256 + k8 * 16;
            byte ^= (row & 7) << 4;
            *(uint4*)(lB + byte) = v;
        }
        __syncthreads();

        f32x4 acc[2][8];
        for (int r = 0; r < 2; ++r)
            for (int c = 0; c < 8; ++c) acc[r][c] = (f32x4)(0.f);

        for (int ks = 0; ks < 4; ++ks) {
            int kbyte = ks * 64 + lk * 16;
            short8 a[2], b[8];
            for (int r = 0; r < 2; ++r) {
                int row = wv * 32 + r * 16 + lr;
                int byte = row * 256 + kbyte;
                byte ^= (row & 7) << 4;
                a[r] = *(const short8*)(lA + byte);
            }
            for (int c = 0; c < 8; ++c) {
                int row = c * 16 + lr;
                int byte = row * 256 + kbyte;
                byte ^= (row & 7) << 4;
                b[c] = *(const short8*)(lB + byte);
            }
            for (int r = 0; r < 2; ++r)
                for (int c = 0; c < 8; ++c)
                    acc[r][c] = __builtin_amdgcn_mfma_f32_16x16x32_bf16(a[r], b[c], acc[r][c], 0, 0, 0);
        }

        for (int r = 0; r < 2; ++r) {
            for (int c = 0; c < 8; ++c) {
                int col = c * 16 + lr;
                for (int i = 0; i < 4; ++i) {
                    int row = r0 + wv * 32 + r * 16 + lk * 4 + i;
                    if (row >= N) continue;
                    float val = acc[r][c][i];
                    size_t off = (size_t)row * D + col;
                    if (widx == 0)      out0[off] = val + bln[col];
                    else if (widx == 1) h1[off] = f2bf(val);
                    else                h2[off] = f2bf(val);
                }
            }
        }
    }
}

// ---- CSR build: histogram over concatenated bins [0, 2*(N+1))
__global__ void hist_k(const int* __restrict__ ei1, const int* __restrict__ ei2,
                       int E1, int E2, int* __restrict__ cnt, int N1) {
    int g = blockIdx.x * blockDim.x + threadIdx.x;
    if (g < E1) {
        atomicAdd(&cnt[ei1[E1 + g]], 1);
    } else if (g < E1 + E2) {
        int e = g - E1;
        atomicAdd(&cnt[N1 + ei2[E2 + e]], 1);
    }
}

// ---- exclusive scan, 1024 elems/block (256 thr x 4)
__global__ void scan1_k(const int* __restrict__ cnt, int* __restrict__ excl,
                        int* __restrict__ bsum, int n) {
    __shared__ int s[256];
    int t = threadIdx.x;
    int base = blockIdx.x * 1024 + t * 4;
    int v0 = 0, v1 = 0, v2 = 0, v3 = 0;
    if (base + 3 < n) {
        int4 q = *(const int4*)(cnt + base);
        v0 = q.x; v1 = q.y; v2 = q.z; v3 = q.w;
    } else {
        if (base < n) v0 = cnt[base];
        if (base + 1 < n) v1 = cnt[base + 1];
        if (base + 2 < n) v2 = cnt[base + 2];
    }
    int sum = v0 + v1 + v2 + v3;
    s[t] = sum; __syncthreads();
    for (int off = 1; off < 256; off <<= 1) {
        int x = (t >= off) ? s[t - off] : 0;
        __syncthreads();
        s[t] += x;
        __syncthreads();
    }
    if (t == 255) bsum[blockIdx.x] = s[255];
    int run = s[t] - sum;
    if (base < n) excl[base] = run;
    if (base + 1 < n) excl[base + 1] = run + v0;
    if (base + 2 < n) excl[base + 2] = run + v0 + v1;
    if (base + 3 < n) excl[base + 3] = run + v0 + v1 + v2;
}

__global__ void scan2_k(int* __restrict__ bsum, int nb) {
    __shared__ int s[256];
    int t = threadIdx.x;
    int v = (t < nb) ? bsum[t] : 0;
    s[t] = v; __syncthreads();
    for (int off = 1; off < 256; off <<= 1) {
        int x = (t >= off) ? s[t - off] : 0;
        __syncthreads();
        s[t] += x;
        __syncthreads();
    }
    if (t < nb) bsum[t] = s[t] - v;
}

__global__ void scan3_k(int* __restrict__ excl, const int* __restrict__ bsum, int n) {
    int i = blockIdx.x * blockDim.x + threadIdx.x;
    if (i < n) excl[i] += bsum[i >> 10];
}

// ---- fill slots: slot[rowptr[bin]+pos] = {src, w}
__global__ void fill_k(const int* __restrict__ ei1, const float* __restrict__ ew1,
                       const int* __restrict__ ei2, const float* __restrict__ ew2,
                       int E1, int E2, const int* __restrict__ rowptr,
                       int* __restrict__ cursor, uint2* __restrict__ slots, int N1) {
    int g = blockIdx.x * blockDim.x + threadIdx.x;
    int src, bin; float w;
    if (g < E1) {
        src = ei1[g]; bin = ei1[E1 + g]; w = ew1[g];
    } else if (g < E1 + E2) {
        int e = g - E1;
        src = ei2[e]; bin = N1 + ei2[E2 + e]; w = ew2[e];
    } else return;
    int pos = atomicAdd(&cursor[bin], 1);
    uint2 v; v.x = (unsigned)src; v.y = __float_as_uint(w);
    slots[rowptr[bin] + pos] = v;
}

// ---- gather: one wave per (branch,node); out = bias + sum w*h[src]
__launch_bounds__(256)
__global__ void gather_k(const uint2* __restrict__ slots, const int* __restrict__ rowptr,
                         const unsigned short* __restrict__ h1, const unsigned short* __restrict__ h2,
                         const float* __restrict__ b1, const float* __restrict__ b2,
                         float* __restrict__ out12, int N, int N1) {
    int wave = (blockIdx.x * 256 + threadIdx.x) >> 6;   // [0, 2N)
    int lane = threadIdx.x & 63;
    if (wave >= 2 * N) return;
    int br = wave >= N;
    int node = wave - br * N;
    int rp = br * N1 + node;
    int beg = rowptr[rp], end = rowptr[rp + 1];
    const unsigned short* h = br ? h2 : h1;
    const float* bias = br ? b2 : b1;
    float a0 = 0.f, a1 = 0.f;
    int j = beg;
    for (; j + 1 < end; j += 2) {
        uint2 s0 = slots[j], s1 = slots[j + 1];
        uint32_t p0 = *(const uint32_t*)(h + (size_t)s0.x * D + lane * 2);
        uint32_t p1 = *(const uint32_t*)(h + (size_t)s1.x * D + lane * 2);
        float w0 = __uint_as_float(s0.y), w1 = __uint_as_float(s1.y);
        a0 += w0 * bf2f(p0 & 0xFFFFu) + w1 * bf2f(p1 & 0xFFFFu);
        a1 += w0 * bf2f(p0 >> 16)     + w1 * bf2f(p1 >> 16);
    }
    if (j < end) {
        uint2 s0 = slots[j];
        uint32_t p0 = *(const uint32_t*)(h + (size_t)s0.x * D + lane * 2);
        float w0 = __uint_as_float(s0.y);
        a0 += w0 * bf2f(p0 & 0xFFFFu);
        a1 += w0 * bf2f(p0 >> 16);
    }
    float2 bv = *(const float2*)(bias + lane * 2);
    float2 ov; ov.x = a0 + bv.x; ov.y = a1 + bv.y;
    *(float2*)(out12 + (size_t)wave * D + lane * 2) = ov;
}

extern "C" void kernel_launch(void* const* d_in, const int* in_sizes, int n_in,
                              void* d_out, int out_size, void* d_ws, size_t ws_size,
                              hipStream_t stream) {
    const float* x   = (const float*)d_in[0];
    const int*   ei1 = (const int*)d_in[1];
    const float* ew1 = (const float*)d_in[2];
    const int*   ei2 = (const int*)d_in[3];
    const float* ew2 = (const float*)d_in[4];
    const float* Wln = (const float*)d_in[5];
    const float* bln = (const float*)d_in[6];
    const float* W1  = (const float*)d_in[7];
    const float* b1  = (const float*)d_in[8];
    const float* W2  = (const float*)d_in[9];
    const float* b2  = (const float*)d_in[10];

    const int N  = in_sizes[0] / D;
    const int E1 = in_sizes[2];
    const int E2 = in_sizes[4];
    const int N1 = N + 1;
    const int n  = 2 * N1;                 // concatenated bins
    const int nb = (n + 1023) / 1024;      // scan blocks (<=256)

    float* out0  = (float*)d_out;
    float* out12 = out0 + (size_t)N * D;   // out1 then out2, contiguous

    // ws layout (64B aligned regions)
    char* ws = (char*)d_ws;
    size_t off = 0;
    auto alloc = [&](size_t bytes) { char* p = ws + off; off += (bytes + 63) & ~(size_t)63; return p; };
    unsigned short* h1     = (unsigned short*)alloc((size_t)N * D * 2);
    unsigned short* h2     = (unsigned short*)alloc((size_t)N * D * 2);
    unsigned short* Wt     = (unsigned short*)alloc(3 * D * D * 2);
    int*            cnt    = (int*)alloc((size_t)2 * n * 4);  // cnt AND cursor, contiguous
    int*            cursor = cnt + n;
    int*            rowptr = (int*)alloc((size_t)n * 4);
    int*            bsum   = (int*)alloc(1024);
    uint2*          slots  = (uint2*)alloc((size_t)(E1 + E2) * 8);

    prep_weights<<<(3 * D * D + 255) / 256, 256, 0, stream>>>(Wln, W1, W2, Wt);
    gemm3<<<(N + 127) / 128, 256, 0, stream>>>(x, Wt, bln, out0, h1, h2, N);

    zero_k<<<512, 256, 0, stream>>>(cnt, 2 * n);   // zeroes cnt AND cursor (one region)
    hist_k<<<(E1 + E2 + 255) / 256, 256, 0, stream>>>(ei1, ei2, E1, E2, cnt, N1);
    scan1_k<<<nb, 256, 0, stream>>>(cnt, rowptr, bsum, n);
    scan2_k<<<1, 256, 0, stream>>>(bsum, nb);
    scan3_k<<<(n + 255) / 256, 256, 0, stream>>>(rowptr, bsum, n);
    fill_k<<<(E1 + E2 + 255) / 256, 256, 0, stream>>>(ei1, ew1, ei2, ew2, E1, E2,
                                                      rowptr, cursor, slots, N1);
    gather_k<<<(2 * N + 3) / 4, 256, 0, stream>>>(slots, rowptr, h1, h2, b1, b2,
                                                  out12, N, N1);
}

// Round 4
// 272.378 us; speedup vs baseline: 4.3221x; 1.4985x over previous
//
#include <hip/hip_runtime.h>
#include <hip/hip_bf16.h>
#include <stdint.h>

#define D 128

typedef __attribute__((ext_vector_type(8))) short short8;
typedef __attribute__((ext_vector_type(4))) float f32x4;

__device__ inline unsigned short f2bf(float f) {
    union { float f; uint32_t u; } v; v.f = f;
    uint32_t u = v.u;
    uint32_t r = u + 0x7FFFu + ((u >> 16) & 1u);   // RNE
    return (unsigned short)(r >> 16);
}

__device__ inline float bf2f(uint32_t ubf) {
    union { uint32_t u; float f; } v; v.u = ubf << 16; return v.f;
}

// ---- prep: Wt[w][c][k] = bf16(W_w[k][c])
__global__ void prep_weights(const float* __restrict__ W0, const float* __restrict__ W1,
                             const float* __restrict__ W2, unsigned short* __restrict__ Wt) {
    int idx = blockIdx.x * blockDim.x + threadIdx.x;
    if (idx >= 3 * D * D) return;
    int w = idx / (D * D);
    int rem = idx - w * D * D;
    int c = rem / D, k = rem - c * D;
    const float* W = (w == 0) ? W0 : ((w == 1) ? W1 : W2);
    Wt[idx] = f2bf(W[k * D + c]);
}

// ---- zero fill (int), grid-stride
__global__ void zero_k(int* __restrict__ p, int n) {
    for (int i = blockIdx.x * blockDim.x + threadIdx.x; i < n; i += gridDim.x * blockDim.x)
        p[i] = 0;
}

// ---- fused GEMM: out0 = x@Wln + bln (f32), h1 = bf16(x@W1), h2 = bf16(x@W2)
// 64-row tile, 4 waves (16 rows each), A-frags in regs, B per-widx in LDS,
// bf16 epilogue staged through LDS for full-line coalesced writes.
__launch_bounds__(256, 2)
__global__ void gemm3(const float* __restrict__ x, const unsigned short* __restrict__ Wt,
                      const float* __restrict__ bln, float* __restrict__ out0,
                      unsigned short* __restrict__ h1, unsigned short* __restrict__ h2, int N) {
    __shared__ char lA[64 * 256];    // A stage (swizzled), later bf16 C-tile stage
    __shared__ char lB[D * 256];     // B stage (swizzled)
    const int tid = threadIdx.x;
    const int r0 = blockIdx.x * 64;

    // stage A: x[r0..r0+64) f32 -> bf16, swizzled
    for (int i = 0; i < 8; ++i) {
        int idx4 = i * 256 + tid;        // float4 index (2048 total)
        int row = idx4 >> 5;             // 32 float4 per row
        int k4 = idx4 & 31;
        float4 v = make_float4(0.f, 0.f, 0.f, 0.f);
        int grow = r0 + row;
        if (grow < N) v = *(const float4*)(x + (size_t)grow * D + k4 * 4);
        uint32_t lo = (uint32_t)f2bf(v.x) | ((uint32_t)f2bf(v.y) << 16);
        uint32_t hi = (uint32_t)f2bf(v.z) | ((uint32_t)f2bf(v.w) << 16);
        int byte = row * 256 + k4 * 8;
        byte ^= (row & 7) << 4;
        *(uint2*)(lA + byte) = make_uint2(lo, hi);
    }
    __syncthreads();

    const int wv = tid >> 6, lane = tid & 63;
    const int lr = lane & 15, lk = lane >> 4;

    // extract A fragments to registers (wave wv owns rows wv*16..wv*16+15)
    short8 afr[4];
    {
        int row = wv * 16 + lr;
        for (int ks = 0; ks < 4; ++ks) {
            int byte = row * 256 + ks * 64 + lk * 16;
            byte ^= (row & 7) << 4;
            afr[ks] = *(const short8*)(lA + byte);
        }
    }
    float blnv[8];
    for (int c = 0; c < 8; ++c) blnv[c] = bln[c * 16 + lr];

    for (int widx = 0; widx < 3; ++widx) {
        __syncthreads();   // lB free (prev MFMA done); lA free (prev epilogue reads done)
        const uint4* src = (const uint4*)(Wt + widx * D * D);
        for (int i = 0; i < 8; ++i) {
            int idx16 = i * 256 + tid;   // 16B chunk (2048 total)
            int row = idx16 >> 4;
            int k8 = idx16 & 15;
            uint4 v = src[idx16];
            int byte = row * 256 + k8 * 16;
            byte ^= (row & 7) << 4;
            *(uint4*)(lB + byte) = v;
        }
        __syncthreads();

        f32x4 acc[8];
        for (int c = 0; c < 8; ++c) acc[c] = (f32x4)(0.f);

        for (int ks = 0; ks < 4; ++ks) {
            short8 b[8];
            for (int c = 0; c < 8; ++c) {
                int row = c * 16 + lr;
                int byte = row * 256 + ks * 64 + lk * 16;
                byte ^= (row & 7) << 4;
                b[c] = *(const short8*)(lB + byte);
            }
            for (int c = 0; c < 8; ++c)
                acc[c] = __builtin_amdgcn_mfma_f32_16x16x32_bf16(afr[ks], b[c], acc[c], 0, 0, 0);
        }

        // C/D mapping: col=lane&15, row=(lane>>4)*4+i
        if (widx == 0) {
            for (int c = 0; c < 8; ++c) {
                int col = c * 16 + lr;
                for (int i = 0; i < 4; ++i) {
                    int grow = r0 + wv * 16 + lk * 4 + i;
                    if (grow < N)
                        out0[(size_t)grow * D + col] = acc[c][i] + blnv[c];
                }
            }
        } else {
            // stage bf16 C-tile into lA (row-XOR swizzle to spread banks)
            for (int c = 0; c < 8; ++c) {
                int col = c * 16 + lr;
                for (int i = 0; i < 4; ++i) {
                    int row_l = wv * 16 + lk * 4 + i;
                    int lin = row_l * 256 + col * 2;
                    int b = lin ^ ((row_l & 7) << 5);
                    *(unsigned short*)(lA + b) = f2bf(acc[c][i]);
                }
            }
            __syncthreads();
            unsigned short* h = (widx == 1) ? h1 : h2;
            for (int i = 0; i < 4; ++i) {
                int idx = i * 256 + tid;      // uint4 index (1024 total)
                int lin = idx * 16;
                int row_l = lin >> 8;
                int rb = lin ^ ((row_l & 7) << 5);
                uint4 v = *(const uint4*)(lA + rb);
                int grow = r0 + row_l;
                if (grow < N)
                    *(uint4*)((char*)h + (size_t)grow * 256 + (lin & 255)) = v;
            }
        }
    }
}

// ---- CSR build: histogram over concatenated bins [0, 2*(N+1))
__global__ void hist_k(const int* __restrict__ ei1, const int* __restrict__ ei2,
                       int E1, int E2, int* __restrict__ cnt, int N1) {
    int g = blockIdx.x * blockDim.x + threadIdx.x;
    if (g < E1) {
        atomicAdd(&cnt[ei1[E1 + g]], 1);
    } else if (g < E1 + E2) {
        int e = g - E1;
        atomicAdd(&cnt[N1 + ei2[E2 + e]], 1);
    }
}

// ---- exclusive scan, 1024 elems/block (256 thr x 4)
__global__ void scan1_k(const int* __restrict__ cnt, int* __restrict__ excl,
                        int* __restrict__ bsum, int n) {
    __shared__ int s[256];
    int t = threadIdx.x;
    int base = blockIdx.x * 1024 + t * 4;
    int v0 = 0, v1 = 0, v2 = 0, v3 = 0;
    if (base + 3 < n) {
        int4 q = *(const int4*)(cnt + base);
        v0 = q.x; v1 = q.y; v2 = q.z; v3 = q.w;
    } else {
        if (base < n) v0 = cnt[base];
        if (base + 1 < n) v1 = cnt[base + 1];
        if (base + 2 < n) v2 = cnt[base + 2];
    }
    int sum = v0 + v1 + v2 + v3;
    s[t] = sum; __syncthreads();
    for (int off = 1; off < 256; off <<= 1) {
        int x = (t >= off) ? s[t - off] : 0;
        __syncthreads();
        s[t] += x;
        __syncthreads();
    }
    if (t == 255) bsum[blockIdx.x] = s[255];
    int run = s[t] - sum;
    if (base < n) excl[base] = run;
    if (base + 1 < n) excl[base + 1] = run + v0;
    if (base + 2 < n) excl[base + 2] = run + v0 + v1;
    if (base + 3 < n) excl[base + 3] = run + v0 + v1 + v2;
}

__global__ void scan2_k(int* __restrict__ bsum, int nb) {
    __shared__ int s[256];
    int t = threadIdx.x;
    int v = (t < nb) ? bsum[t] : 0;
    s[t] = v; __syncthreads();
    for (int off = 1; off < 256; off <<= 1) {
        int x = (t >= off) ? s[t - off] : 0;
        __syncthreads();
        s[t] += x;
        __syncthreads();
    }
    if (t < nb) bsum[t] = s[t] - v;
}

__global__ void scan3_k(int* __restrict__ excl, const int* __restrict__ bsum, int n) {
    int i = blockIdx.x * blockDim.x + threadIdx.x;
    if (i < n) excl[i] += bsum[i >> 10];
}

// ---- fill slots: slot[rowptr[bin]+pos] = {src, w}
__global__ void fill_k(const int* __restrict__ ei1, const float* __restrict__ ew1,
                       const int* __restrict__ ei2, const float* __restrict__ ew2,
                       int E1, int E2, const int* __restrict__ rowptr,
                       int* __restrict__ cursor, uint2* __restrict__ slots, int N1) {
    int g = blockIdx.x * blockDim.x + threadIdx.x;
    int src, bin; float w;
    if (g < E1) {
        src = ei1[g]; bin = ei1[E1 + g]; w = ew1[g];
    } else if (g < E1 + E2) {
        int e = g - E1;
        src = ei2[e]; bin = N1 + ei2[E2 + e]; w = ew2[e];
    } else return;
    int pos = atomicAdd(&cursor[bin], 1);
    uint2 v; v.x = (unsigned)src; v.y = __float_as_uint(w);
    slots[rowptr[bin] + pos] = v;
}

// ---- gather: one wave per (branch,node); out = bias + sum w*h[src]
__launch_bounds__(256)
__global__ void gather_k(const uint2* __restrict__ slots, const int* __restrict__ rowptr,
                         const unsigned short* __restrict__ h1, const unsigned short* __restrict__ h2,
                         const float* __restrict__ b1, const float* __restrict__ b2,
                         float* __restrict__ out12, int N, int N1) {
    int wave = (blockIdx.x * 256 + threadIdx.x) >> 6;   // [0, 2N)
    int lane = threadIdx.x & 63;
    if (wave >= 2 * N) return;
    int br = wave >= N;
    int node = wave - br * N;
    int rp = br * N1 + node;
    int beg = rowptr[rp], end = rowptr[rp + 1];
    const unsigned short* h = br ? h2 : h1;
    const float* bias = br ? b2 : b1;
    float a0 = 0.f, a1 = 0.f;
    int j = beg;
    for (; j + 1 < end; j += 2) {
        uint2 s0 = slots[j], s1 = slots[j + 1];
        uint32_t p0 = *(const uint32_t*)(h + (size_t)s0.x * D + lane * 2);
        uint32_t p1 = *(const uint32_t*)(h + (size_t)s1.x * D + lane * 2);
        float w0 = __uint_as_float(s0.y), w1 = __uint_as_float(s1.y);
        a0 += w0 * bf2f(p0 & 0xFFFFu) + w1 * bf2f(p1 & 0xFFFFu);
        a1 += w0 * bf2f(p0 >> 16)     + w1 * bf2f(p1 >> 16);
    }
    if (j < end) {
        uint2 s0 = slots[j];
        uint32_t p0 = *(const uint32_t*)(h + (size_t)s0.x * D + lane * 2);
        float w0 = __uint_as_float(s0.y);
        a0 += w0 * bf2f(p0 & 0xFFFFu);
        a1 += w0 * bf2f(p0 >> 16);
    }
    float2 bv = *(const float2*)(bias + lane * 2);
    float2 ov; ov.x = a0 + bv.x; ov.y = a1 + bv.y;
    *(float2*)(out12 + (size_t)wave * D + lane * 2) = ov;
}

extern "C" void kernel_launch(void* const* d_in, const int* in_sizes, int n_in,
                              void* d_out, int out_size, void* d_ws, size_t ws_size,
                              hipStream_t stream) {
    const float* x   = (const float*)d_in[0];
    const int*   ei1 = (const int*)d_in[1];
    const float* ew1 = (const float*)d_in[2];
    const int*   ei2 = (const int*)d_in[3];
    const float* ew2 = (const float*)d_in[4];
    const float* Wln = (const float*)d_in[5];
    const float* bln = (const float*)d_in[6];
    const float* W1  = (const float*)d_in[7];
    const float* b1  = (const float*)d_in[8];
    const float* W2  = (const float*)d_in[9];
    const float* b2  = (const float*)d_in[10];

    const int N  = in_sizes[0] / D;
    const int E1 = in_sizes[2];
    const int E2 = in_sizes[4];
    const int N1 = N + 1;
    const int n  = 2 * N1;                 // concatenated bins
    const int nb = (n + 1023) / 1024;      // scan blocks (<=256)

    float* out0  = (float*)d_out;
    float* out12 = out0 + (size_t)N * D;   // out1 then out2, contiguous

    // ws layout (64B aligned regions)
    char* ws = (char*)d_ws;
    size_t off = 0;
    auto alloc = [&](size_t bytes) { char* p = ws + off; off += (bytes + 63) & ~(size_t)63; return p; };
    unsigned short* h1     = (unsigned short*)alloc((size_t)N * D * 2);
    unsigned short* h2     = (unsigned short*)alloc((size_t)N * D * 2);
    unsigned short* Wt     = (unsigned short*)alloc(3 * D * D * 2);
    int*            cnt    = (int*)alloc((size_t)2 * n * 4);  // cnt AND cursor, contiguous
    int*            cursor = cnt + n;
    int*            rowptr = (int*)alloc((size_t)n * 4);
    int*            bsum   = (int*)alloc(1024);
    uint2*          slots  = (uint2*)alloc((size_t)(E1 + E2) * 8);

    prep_weights<<<(3 * D * D + 255) / 256, 256, 0, stream>>>(Wln, W1, W2, Wt);
    gemm3<<<(N + 63) / 64, 256, 0, stream>>>(x, Wt, bln, out0, h1, h2, N);

    zero_k<<<512, 256, 0, stream>>>(cnt, 2 * n);   // zeroes cnt AND cursor (one region)
    hist_k<<<(E1 + E2 + 255) / 256, 256, 0, stream>>>(ei1, ei2, E1, E2, cnt, N1);
    scan1_k<<<nb, 256, 0, stream>>>(cnt, rowptr, bsum, n);
    scan2_k<<<1, 256, 0, stream>>>(bsum, nb);
    scan3_k<<<(n + 255) / 256, 256, 0, stream>>>(rowptr, bsum, n);
    fill_k<<<(E1 + E2 + 255) / 256, 256, 0, stream>>>(ei1, ew1, ei2, ew2, E1, E2,
                                                      rowptr, cursor, slots, N1);
    gather_k<<<(2 * N + 3) / 4, 256, 0, stream>>>(slots, rowptr, h1, h2, b1, b2,
                                                  out12, N, N1);
}

// Round 5
// 254.842 us; speedup vs baseline: 4.6195x; 1.0688x over previous
//
#include <hip/hip_runtime.h>
#include <hip/hip_bf16.h>
#include <stdint.h>

#define D 128

typedef __attribute__((ext_vector_type(8))) short short8;
typedef __attribute__((ext_vector_type(4))) float f32x4;

__device__ inline unsigned short f2bf(float f) {
    union { float f; uint32_t u; } v; v.f = f;
    uint32_t u = v.u;
    uint32_t r = u + 0x7FFFu + ((u >> 16) & 1u);   // RNE
    return (unsigned short)(r >> 16);
}

__device__ inline float bf2f(uint32_t ubf) {
    union { uint32_t u; float f; } v; v.u = ubf << 16; return v.f;
}

// ---- prep: Wt[w][c][k] = bf16(W_w[k][c])
__global__ void prep_weights(const float* __restrict__ W0, const float* __restrict__ W1,
                             const float* __restrict__ W2, unsigned short* __restrict__ Wt) {
    int idx = blockIdx.x * blockDim.x + threadIdx.x;
    if (idx >= 3 * D * D) return;
    int w = idx / (D * D);
    int rem = idx - w * D * D;
    int c = rem / D, k = rem - c * D;
    const float* W = (w == 0) ? W0 : ((w == 1) ? W1 : W2);
    Wt[idx] = f2bf(W[k * D + c]);
}

// ---- zero fill (int), grid-stride
__global__ void zero_k(int* __restrict__ p, int n) {
    for (int i = blockIdx.x * blockDim.x + threadIdx.x; i < n; i += gridDim.x * blockDim.x)
        p[i] = 0;
}

// ---- fused GEMM: out0 = x@Wln + bln (f32), h1 = bf16(x@W1), h2 = bf16(x@W2)
__launch_bounds__(256, 2)
__global__ void gemm3(const float* __restrict__ x, const unsigned short* __restrict__ Wt,
                      const float* __restrict__ bln, float* __restrict__ out0,
                      unsigned short* __restrict__ h1, unsigned short* __restrict__ h2, int N) {
    __shared__ char lA[64 * 256];    // A stage (swizzled), later bf16 C-tile stage
    __shared__ char lB[D * 256];     // B stage (swizzled)
    const int tid = threadIdx.x;
    const int r0 = blockIdx.x * 64;

    for (int i = 0; i < 8; ++i) {
        int idx4 = i * 256 + tid;
        int row = idx4 >> 5;
        int k4 = idx4 & 31;
        float4 v = make_float4(0.f, 0.f, 0.f, 0.f);
        int grow = r0 + row;
        if (grow < N) v = *(const float4*)(x + (size_t)grow * D + k4 * 4);
        uint32_t lo = (uint32_t)f2bf(v.x) | ((uint32_t)f2bf(v.y) << 16);
        uint32_t hi = (uint32_t)f2bf(v.z) | ((uint32_t)f2bf(v.w) << 16);
        int byte = row * 256 + k4 * 8;
        byte ^= (row & 7) << 4;
        *(uint2*)(lA + byte) = make_uint2(lo, hi);
    }
    __syncthreads();

    const int wv = tid >> 6, lane = tid & 63;
    const int lr = lane & 15, lk = lane >> 4;

    short8 afr[4];
    {
        int row = wv * 16 + lr;
        for (int ks = 0; ks < 4; ++ks) {
            int byte = row * 256 + ks * 64 + lk * 16;
            byte ^= (row & 7) << 4;
            afr[ks] = *(const short8*)(lA + byte);
        }
    }
    float blnv[8];
    for (int c = 0; c < 8; ++c) blnv[c] = bln[c * 16 + lr];

    for (int widx = 0; widx < 3; ++widx) {
        __syncthreads();
        const uint4* src = (const uint4*)(Wt + widx * D * D);
        for (int i = 0; i < 8; ++i) {
            int idx16 = i * 256 + tid;
            int row = idx16 >> 4;
            int k8 = idx16 & 15;
            uint4 v = src[idx16];
            int byte = row * 256 + k8 * 16;
            byte ^= (row & 7) << 4;
            *(uint4*)(lB + byte) = v;
        }
        __syncthreads();

        f32x4 acc[8];
        for (int c = 0; c < 8; ++c) acc[c] = (f32x4)(0.f);

        for (int ks = 0; ks < 4; ++ks) {
            short8 b[8];
            for (int c = 0; c < 8; ++c) {
                int row = c * 16 + lr;
                int byte = row * 256 + ks * 64 + lk * 16;
                byte ^= (row & 7) << 4;
                b[c] = *(const short8*)(lB + byte);
            }
            for (int c = 0; c < 8; ++c)
                acc[c] = __builtin_amdgcn_mfma_f32_16x16x32_bf16(afr[ks], b[c], acc[c], 0, 0, 0);
        }

        if (widx == 0) {
            for (int c = 0; c < 8; ++c) {
                int col = c * 16 + lr;
                for (int i = 0; i < 4; ++i) {
                    int grow = r0 + wv * 16 + lk * 4 + i;
                    if (grow < N)
                        out0[(size_t)grow * D + col] = acc[c][i] + blnv[c];
                }
            }
        } else {
            for (int c = 0; c < 8; ++c) {
                int col = c * 16 + lr;
                for (int i = 0; i < 4; ++i) {
                    int row_l = wv * 16 + lk * 4 + i;
                    int lin = row_l * 256 + col * 2;
                    int b = lin ^ ((row_l & 7) << 5);
                    *(unsigned short*)(lA + b) = f2bf(acc[c][i]);
                }
            }
            __syncthreads();
            unsigned short* h = (widx == 1) ? h1 : h2;
            for (int i = 0; i < 4; ++i) {
                int idx = i * 256 + tid;
                int lin = idx * 16;
                int row_l = lin >> 8;
                int rb = lin ^ ((row_l & 7) << 5);
                uint4 v = *(const uint4*)(lA + rb);
                int grow = r0 + row_l;
                if (grow < N)
                    *(uint4*)((char*)h + (size_t)grow * 256 + (lin & 255)) = v;
            }
        }
    }
}

// ---- CSR build: histogram over concatenated bins [0, 2*(N+1))
__global__ void hist_k(const int* __restrict__ ei1, const int* __restrict__ ei2,
                       int E1, int E2, int* __restrict__ cnt, int N1) {
    int g = blockIdx.x * blockDim.x + threadIdx.x;
    if (g < E1) {
        atomicAdd(&cnt[ei1[E1 + g]], 1);
    } else if (g < E1 + E2) {
        int e = g - E1;
        atomicAdd(&cnt[N1 + ei2[E2 + e]], 1);
    }
}

// ---- exclusive scan, 1024 elems/block (256 thr x 4)
__global__ void scan1_k(const int* __restrict__ cnt, int* __restrict__ excl,
                        int* __restrict__ bsum, int n) {
    __shared__ int s[256];
    int t = threadIdx.x;
    int base = blockIdx.x * 1024 + t * 4;
    int v0 = 0, v1 = 0, v2 = 0, v3 = 0;
    if (base + 3 < n) {
        int4 q = *(const int4*)(cnt + base);
        v0 = q.x; v1 = q.y; v2 = q.z; v3 = q.w;
    } else {
        if (base < n) v0 = cnt[base];
        if (base + 1 < n) v1 = cnt[base + 1];
        if (base + 2 < n) v2 = cnt[base + 2];
    }
    int sum = v0 + v1 + v2 + v3;
    s[t] = sum; __syncthreads();
    for (int off = 1; off < 256; off <<= 1) {
        int x = (t >= off) ? s[t - off] : 0;
        __syncthreads();
        s[t] += x;
        __syncthreads();
    }
    if (t == 255) bsum[blockIdx.x] = s[255];
    int run = s[t] - sum;
    if (base < n) excl[base] = run;
    if (base + 1 < n) excl[base + 1] = run + v0;
    if (base + 2 < n) excl[base + 2] = run + v0 + v1;
    if (base + 3 < n) excl[base + 3] = run + v0 + v1 + v2;
}

__global__ void scan2_k(int* __restrict__ bsum, int nb) {
    __shared__ int s[256];
    int t = threadIdx.x;
    int v = (t < nb) ? bsum[t] : 0;
    s[t] = v; __syncthreads();
    for (int off = 1; off < 256; off <<= 1) {
        int x = (t >= off) ? s[t - off] : 0;
        __syncthreads();
        s[t] += x;
        __syncthreads();
    }
    if (t < nb) bsum[t] = s[t] - v;
}

__global__ void scan3_k(int* __restrict__ excl, const int* __restrict__ bsum, int n) {
    int i = blockIdx.x * blockDim.x + threadIdx.x;
    if (i < n) excl[i] += bsum[i >> 10];
}

// ---- fill slots: slot[rowptr[bin]+pos] = {src, w}
__global__ void fill_k(const int* __restrict__ ei1, const float* __restrict__ ew1,
                       const int* __restrict__ ei2, const float* __restrict__ ew2,
                       int E1, int E2, const int* __restrict__ rowptr,
                       int* __restrict__ cursor, uint2* __restrict__ slots, int N1) {
    int g = blockIdx.x * blockDim.x + threadIdx.x;
    int src, bin; float w;
    if (g < E1) {
        src = ei1[g]; bin = ei1[E1 + g]; w = ew1[g];
    } else if (g < E1 + E2) {
        int e = g - E1;
        src = ei2[e]; bin = N1 + ei2[E2 + e]; w = ew2[e];
    } else return;
    int pos = atomicAdd(&cursor[bin], 1);
    uint2 v; v.x = (unsigned)src; v.y = __float_as_uint(w);
    slots[rowptr[bin] + pos] = v;
}

// ---- gather: one wave per (branch,node); half-wave edge pairing.
// lane = 32*half + sl; lane covers features 4*sl..4*sl+3 (8B of h row).
// half 0 processes edges beg,beg+2,..., half 1 edges beg+1,beg+3,...
// 2x unroll per half -> up to 4 slot->h chains in flight per wave.
__launch_bounds__(256)
__global__ void gather_k(const uint2* __restrict__ slots, const int* __restrict__ rowptr,
                         const unsigned short* __restrict__ h1, const unsigned short* __restrict__ h2,
                         const float* __restrict__ b1, const float* __restrict__ b2,
                         float* __restrict__ out12, int N, int N1) {
    int wave = (blockIdx.x * 256 + threadIdx.x) >> 6;   // [0, 2N)
    int lane = threadIdx.x & 63;
    if (wave >= 2 * N) return;
    int half = lane >> 5, sl = lane & 31;
    int br = wave >= N;
    int node = wave - br * N;
    int rp = br * N1 + node;
    int beg = rowptr[rp], end = rowptr[rp + 1];
    const unsigned short* h = br ? h2 : h1;
    const float* bias = br ? b2 : b1;

    float a0 = 0.f, a1 = 0.f, a2 = 0.f, a3 = 0.f;
    int j = beg + half;
    for (; j + 2 < end; j += 4) {
        uint2 s0 = slots[j], s1 = slots[j + 2];
        uint2 p0 = *(const uint2*)(h + (size_t)s0.x * D + sl * 4);
        uint2 p1 = *(const uint2*)(h + (size_t)s1.x * D + sl * 4);
        float w0 = __uint_as_float(s0.y), w1 = __uint_as_float(s1.y);
        a0 += w0 * bf2f(p0.x & 0xFFFFu) + w1 * bf2f(p1.x & 0xFFFFu);
        a1 += w0 * bf2f(p0.x >> 16)     + w1 * bf2f(p1.x >> 16);
        a2 += w0 * bf2f(p0.y & 0xFFFFu) + w1 * bf2f(p1.y & 0xFFFFu);
        a3 += w0 * bf2f(p0.y >> 16)     + w1 * bf2f(p1.y >> 16);
    }
    if (j < end) {
        uint2 s0 = slots[j];
        uint2 p0 = *(const uint2*)(h + (size_t)s0.x * D + sl * 4);
        float w0 = __uint_as_float(s0.y);
        a0 += w0 * bf2f(p0.x & 0xFFFFu);
        a1 += w0 * bf2f(p0.x >> 16);
        a2 += w0 * bf2f(p0.y & 0xFFFFu);
        a3 += w0 * bf2f(p0.y >> 16);
    }
    // combine halves (both halves hold partials for the same features)
    a0 += __shfl_xor(a0, 32);
    a1 += __shfl_xor(a1, 32);
    a2 += __shfl_xor(a2, 32);
    a3 += __shfl_xor(a3, 32);
    if (half == 0) {
        float4 bv = *(const float4*)(bias + sl * 4);
        float4 ov;
        ov.x = a0 + bv.x; ov.y = a1 + bv.y; ov.z = a2 + bv.z; ov.w = a3 + bv.w;
        *(float4*)(out12 + (size_t)wave * D + sl * 4) = ov;
    }
}

extern "C" void kernel_launch(void* const* d_in, const int* in_sizes, int n_in,
                              void* d_out, int out_size, void* d_ws, size_t ws_size,
                              hipStream_t stream) {
    const float* x   = (const float*)d_in[0];
    const int*   ei1 = (const int*)d_in[1];
    const float* ew1 = (const float*)d_in[2];
    const int*   ei2 = (const int*)d_in[3];
    const float* ew2 = (const float*)d_in[4];
    const float* Wln = (const float*)d_in[5];
    const float* bln = (const float*)d_in[6];
    const float* W1  = (const float*)d_in[7];
    const float* b1  = (const float*)d_in[8];
    const float* W2  = (const float*)d_in[9];
    const float* b2  = (const float*)d_in[10];

    const int N  = in_sizes[0] / D;
    const int E1 = in_sizes[2];
    const int E2 = in_sizes[4];
    const int N1 = N + 1;
    const int n  = 2 * N1;
    const int nb = (n + 1023) / 1024;

    float* out0  = (float*)d_out;
    float* out12 = out0 + (size_t)N * D;

    char* ws = (char*)d_ws;
    size_t off = 0;
    auto alloc = [&](size_t bytes) { char* p = ws + off; off += (bytes + 63) & ~(size_t)63; return p; };
    unsigned short* h1     = (unsigned short*)alloc((size_t)N * D * 2);
    unsigned short* h2     = (unsigned short*)alloc((size_t)N * D * 2);
    unsigned short* Wt     = (unsigned short*)alloc(3 * D * D * 2);
    int*            cnt    = (int*)alloc((size_t)2 * n * 4);
    int*            cursor = cnt + n;
    int*            rowptr = (int*)alloc((size_t)n * 4);
    int*            bsum   = (int*)alloc(1024);
    uint2*          slots  = (uint2*)alloc((size_t)(E1 + E2) * 8);

    prep_weights<<<(3 * D * D + 255) / 256, 256, 0, stream>>>(Wln, W1, W2, Wt);
    gemm3<<<(N + 63) / 64, 256, 0, stream>>>(x, Wt, bln, out0, h1, h2, N);

    zero_k<<<512, 256, 0, stream>>>(cnt, 2 * n);
    hist_k<<<(E1 + E2 + 255) / 256, 256, 0, stream>>>(ei1, ei2, E1, E2, cnt, N1);
    scan1_k<<<nb, 256, 0, stream>>>(cnt, rowptr, bsum, n);
    scan2_k<<<1, 256, 0, stream>>>(bsum, nb);
    scan3_k<<<(n + 255) / 256, 256, 0, stream>>>(rowptr, bsum, n);
    fill_k<<<(E1 + E2 + 255) / 256, 256, 0, stream>>>(ei1, ew1, ei2, ew2, E1, E2,
                                                      rowptr, cursor, slots, N1);
    gather_k<<<(2 * N + 3) / 4, 256, 0, stream>>>(slots, rowptr, h1, h2, b1, b2,
                                                  out12, N, N1);
}